// Round 1
// baseline (1467.582 us; speedup 1.0000x reference)
//
#include <hip/hip_runtime.h>
#include <math.h>

#define N_NODES 50000
#define N_EDGES 800000
#define E_TOT   (N_EDGES + N_NODES)   // 850000, self-loops appended
#define NEG_SLOPE 0.2f

// ---- workspace layout (bytes) ----
// zeroed region first (single memsetAsync):
#define OUT1_OFF   0UL              // N*256 f32 = 51,200,000
#define EMAX1_OFF  51200000UL       // N*4 u32   =    800,000
#define DEN1_OFF   52000000UL       // N*4 f32   =    800,000
#define OUT2_OFF   52800000UL       // N*64 f32  = 12,800,000
#define EMAX2_OFF  65600000UL       // N u32     =    200,000
#define DEN2_OFF   65800000UL       // N f32     =    200,000
#define ZERO_BYTES 66000000UL
// non-zeroed:
#define AS1_OFF    66000000UL       // N*4 f32
#define AD1_OFF    66800000UL       // N*4 f32
#define H2_OFF     67600000UL       // N*64 f32
#define AS2_OFF    80400000UL       // N f32
#define AD2_OFF    80600000UL       // N f32

__device__ __forceinline__ float wave_reduce_sum(float v) {
    #pragma unroll
    for (int off = 32; off > 0; off >>= 1) v += __shfl_xor(v, off, 64);
    return v;
}
__device__ __forceinline__ float lrelu(float v) { return v > 0.f ? v : NEG_SLOPE * v; }
__device__ __forceinline__ float elu(float v)   { return v > 0.f ? v : expf(v) - 1.f; }
// monotone float->uint encoding for atomicMax
__device__ __forceinline__ unsigned enc(float f) {
    unsigned u = __float_as_uint(f);
    return (u & 0x80000000u) ? ~u : (u | 0x80000000u);
}
__device__ __forceinline__ float dec(unsigned u) {
    u = (u & 0x80000000u) ? (u ^ 0x80000000u) : ~u;
    return __uint_as_float(u);
}
__device__ __forceinline__ void edge_sd(int e, const int* __restrict__ ei, int& s, int& d) {
    if (e < N_EDGES) { s = ei[e]; d = ei[N_EDGES + e]; }
    else             { s = d = e - N_EDGES; }
}

// K1: per node, h1 = x@W1 (recomputed, not stored); alpha_s1/alpha_d1 via wave reduce.
// block 256 = 4 waves = 4 heads; grid = N_NODES
__global__ void node_prep1(const float* __restrict__ x, const float* __restrict__ W1,
                           const float* __restrict__ a_src, const float* __restrict__ a_dst,
                           float* __restrict__ alpha_s, float* __restrict__ alpha_d) {
    int n = blockIdx.x;
    int head = threadIdx.x >> 6;
    int lane = threadIdx.x & 63;
    float x0 = x[n*3+0], x1 = x[n*3+1], x2 = x[n*3+2];
    int j = head*64 + lane;
    float hv = x0*W1[j] + x1*W1[256+j] + x2*W1[512+j];
    float ps = wave_reduce_sum(hv * a_src[j]);
    float pd = wave_reduce_sum(hv * a_dst[j]);
    if (lane == 0) { alpha_s[n*4+head] = ps; alpha_d[n*4+head] = pd; }
}

// K2: per-edge segment max (4 heads)
__global__ void edge_max1(const int* __restrict__ ei, const float* __restrict__ alpha_s,
                          const float* __restrict__ alpha_d, unsigned* __restrict__ emax) {
    int e = blockIdx.x*blockDim.x + threadIdx.x;
    if (e >= E_TOT) return;
    int s, d; edge_sd(e, ei, s, d);
    float4 as = *(const float4*)(alpha_s + (size_t)s*4);
    float4 ad = *(const float4*)(alpha_d + (size_t)d*4);
    atomicMax(&emax[d*4+0], enc(lrelu(as.x+ad.x)));
    atomicMax(&emax[d*4+1], enc(lrelu(as.y+ad.y)));
    atomicMax(&emax[d*4+2], enc(lrelu(as.z+ad.z)));
    atomicMax(&emax[d*4+3], enc(lrelu(as.w+ad.w)));
}

// K3: per-edge exp-sum (4 heads)
__global__ void edge_sum1(const int* __restrict__ ei, const float* __restrict__ alpha_s,
                          const float* __restrict__ alpha_d, const unsigned* __restrict__ emax,
                          float* __restrict__ denom) {
    int e = blockIdx.x*blockDim.x + threadIdx.x;
    if (e >= E_TOT) return;
    int s, d; edge_sd(e, ei, s, d);
    float4 as = *(const float4*)(alpha_s + (size_t)s*4);
    float4 ad = *(const float4*)(alpha_d + (size_t)d*4);
    atomicAdd(&denom[d*4+0], expf(lrelu(as.x+ad.x) - dec(emax[d*4+0])));
    atomicAdd(&denom[d*4+1], expf(lrelu(as.y+ad.y) - dec(emax[d*4+1])));
    atomicAdd(&denom[d*4+2], expf(lrelu(as.z+ad.z) - dec(emax[d*4+2])));
    atomicAdd(&denom[d*4+3], expf(lrelu(as.w+ad.w) - dec(emax[d*4+3])));
}

// K4: per-edge weighted scatter, one wave per edge, lane = channel, loop heads.
// h1[src] recomputed from x[src] (3 FMAs) -- avoids storing/gathering 1KB rows.
__global__ void edge_agg1(const int* __restrict__ ei, const float* __restrict__ x,
                          const float* __restrict__ W1, const float* __restrict__ alpha_s,
                          const float* __restrict__ alpha_d, const unsigned* __restrict__ emax,
                          const float* __restrict__ denom, float* __restrict__ out1) {
    int wid = (blockIdx.x*blockDim.x + threadIdx.x) >> 6;
    int lane = threadIdx.x & 63;
    if (wid >= E_TOT) return;
    int s, d; edge_sd(wid, ei, s, d);
    float x0 = x[s*3+0], x1 = x[s*3+1], x2 = x[s*3+2];
    float4 as = *(const float4*)(alpha_s + (size_t)s*4);
    float4 ad = *(const float4*)(alpha_d + (size_t)d*4);
    float eh[4] = { lrelu(as.x+ad.x), lrelu(as.y+ad.y), lrelu(as.z+ad.z), lrelu(as.w+ad.w) };
    #pragma unroll
    for (int h = 0; h < 4; ++h) {
        float ex = expf(eh[h] - dec(emax[d*4+h]));
        float alpha = ex / (denom[d*4+h] + 1e-16f);
        int j = h*64 + lane;
        float hv = x0*W1[j] + x1*W1[256+j] + x2*W1[512+j];
        atomicAdd(&out1[(size_t)d*256 + j], hv * alpha);
    }
}

// K5: out1 = elu(out1 + b1), in place (becomes x2). float4 grid-stride.
__global__ void bias_elu1(float* __restrict__ out1, const float* __restrict__ b1) {
    int total = N_NODES * 64;  // float4 count
    for (int i = blockIdx.x*blockDim.x + threadIdx.x; i < total; i += gridDim.x*blockDim.x) {
        float4 v = ((float4*)out1)[i];
        int j = (i * 4) & 255;
        v.x = elu(v.x + b1[j+0]); v.y = elu(v.y + b1[j+1]);
        v.z = elu(v.z + b1[j+2]); v.w = elu(v.w + b1[j+3]);
        ((float4*)out1)[i] = v;
    }
}

// K6: h2 = x2 @ W2 (256->64); alpha_s2/alpha_d2. One wave per node, 4 nodes/block.
__global__ void node_prep2(const float* __restrict__ x2, const float* __restrict__ W2,
                           const float* __restrict__ a_src, const float* __restrict__ a_dst,
                           float* __restrict__ h2, float* __restrict__ alpha_s,
                           float* __restrict__ alpha_d) {
    int n = blockIdx.x*4 + (threadIdx.x >> 6);
    int lane = threadIdx.x & 63;
    if (n >= N_NODES) return;
    const float* xr = x2 + (size_t)n*256;
    float acc = 0.f;
    #pragma unroll
    for (int k0 = 0; k0 < 256; k0 += 64) {
        float xk = xr[k0 + lane];           // coalesced chunk
        #pragma unroll
        for (int k = 0; k < 64; ++k)
            acc += __shfl(xk, k, 64) * W2[(k0+k)*64 + lane];
    }
    h2[(size_t)n*64 + lane] = acc;
    float ps = wave_reduce_sum(acc * a_src[lane]);
    float pd = wave_reduce_sum(acc * a_dst[lane]);
    if (lane == 0) { alpha_s[n] = ps; alpha_d[n] = pd; }
}

// K7/K8: single-head max / sum
__global__ void edge_max2(const int* __restrict__ ei, const float* __restrict__ alpha_s,
                          const float* __restrict__ alpha_d, unsigned* __restrict__ emax) {
    int e = blockIdx.x*blockDim.x + threadIdx.x;
    if (e >= E_TOT) return;
    int s, d; edge_sd(e, ei, s, d);
    atomicMax(&emax[d], enc(lrelu(alpha_s[s] + alpha_d[d])));
}
__global__ void edge_sum2(const int* __restrict__ ei, const float* __restrict__ alpha_s,
                          const float* __restrict__ alpha_d, const unsigned* __restrict__ emax,
                          float* __restrict__ denom) {
    int e = blockIdx.x*blockDim.x + threadIdx.x;
    if (e >= E_TOT) return;
    int s, d; edge_sd(e, ei, s, d);
    atomicAdd(&denom[d], expf(lrelu(alpha_s[s] + alpha_d[d]) - dec(emax[d])));
}

// K9: per-edge weighted scatter layer 2, one wave per edge, lane = channel
__global__ void edge_agg2(const int* __restrict__ ei, const float* __restrict__ h2,
                          const float* __restrict__ alpha_s, const float* __restrict__ alpha_d,
                          const unsigned* __restrict__ emax, const float* __restrict__ denom,
                          float* __restrict__ out2) {
    int wid = (blockIdx.x*blockDim.x + threadIdx.x) >> 6;
    int lane = threadIdx.x & 63;
    if (wid >= E_TOT) return;
    int s, d; edge_sd(wid, ei, s, d);
    float eh = lrelu(alpha_s[s] + alpha_d[d]);
    float alpha = expf(eh - dec(emax[d])) / (denom[d] + 1e-16f);
    atomicAdd(&out2[(size_t)d*64 + lane], h2[(size_t)s*64 + lane] * alpha);
}

// K10: out = sigmoid(elu(out2 + b2) @ Wfc + bfc). One wave per node.
__global__ void final_fc(const float* __restrict__ out2, const float* __restrict__ b2,
                         const float* __restrict__ Wfc, const float* __restrict__ bfc,
                         float* __restrict__ out) {
    int n = blockIdx.x*4 + (threadIdx.x >> 6);
    int lane = threadIdx.x & 63;
    if (n >= N_NODES) return;
    float v = out2[(size_t)n*64 + lane] + b2[lane];
    v = elu(v);
    float sum = wave_reduce_sum(v * Wfc[lane]);
    if (lane == 0) out[n] = 1.f / (1.f + expf(-(sum + bfc[0])));
}

extern "C" void kernel_launch(void* const* d_in, const int* in_sizes, int n_in,
                              void* d_out, int out_size, void* d_ws, size_t ws_size,
                              hipStream_t stream) {
    const float* x      = (const float*)d_in[0];
    const int*   ei     = (const int*)  d_in[1];
    const float* W1     = (const float*)d_in[2];
    const float* a_src1 = (const float*)d_in[3];
    const float* a_dst1 = (const float*)d_in[4];
    const float* b1     = (const float*)d_in[5];
    const float* W2     = (const float*)d_in[6];
    const float* a_src2 = (const float*)d_in[7];
    const float* a_dst2 = (const float*)d_in[8];
    const float* b2     = (const float*)d_in[9];
    const float* Wfc    = (const float*)d_in[10];
    const float* bfc    = (const float*)d_in[11];
    float* out = (float*)d_out;

    char* ws = (char*)d_ws;
    float*    out1  = (float*)   (ws + OUT1_OFF);
    unsigned* emax1 = (unsigned*)(ws + EMAX1_OFF);
    float*    den1  = (float*)   (ws + DEN1_OFF);
    float*    out2  = (float*)   (ws + OUT2_OFF);
    unsigned* emax2 = (unsigned*)(ws + EMAX2_OFF);
    float*    den2  = (float*)   (ws + DEN2_OFF);
    float*    as1   = (float*)   (ws + AS1_OFF);
    float*    ad1   = (float*)   (ws + AD1_OFF);
    float*    h2    = (float*)   (ws + H2_OFF);
    float*    as2   = (float*)   (ws + AS2_OFF);
    float*    ad2   = (float*)   (ws + AD2_OFF);

    // zero accumulators / max-encodings (0u == encoding below any real float)
    hipMemsetAsync(d_ws, 0, ZERO_BYTES, stream);

    const int BLK = 256;
    const int egrid  = (E_TOT + BLK - 1) / BLK;        // 1 thread / edge
    const int ewgrid = (E_TOT + 3) / 4;                 // 1 wave / edge (4 waves/block)
    const int ngrid4 = (N_NODES + 3) / 4;               // 1 wave / node

    node_prep1<<<N_NODES, BLK, 0, stream>>>(x, W1, a_src1, a_dst1, as1, ad1);
    edge_max1 <<<egrid, BLK, 0, stream>>>(ei, as1, ad1, emax1);
    edge_sum1 <<<egrid, BLK, 0, stream>>>(ei, as1, ad1, emax1, den1);
    edge_agg1 <<<ewgrid, BLK, 0, stream>>>(ei, x, W1, as1, ad1, emax1, den1, out1);
    bias_elu1 <<<2048, BLK, 0, stream>>>(out1, b1);
    node_prep2<<<ngrid4, BLK, 0, stream>>>(out1, W2, a_src2, a_dst2, h2, as2, ad2);
    edge_max2 <<<egrid, BLK, 0, stream>>>(ei, as2, ad2, emax2);
    edge_sum2 <<<egrid, BLK, 0, stream>>>(ei, as2, ad2, emax2, den2);
    edge_agg2 <<<ewgrid, BLK, 0, stream>>>(ei, h2, as2, ad2, emax2, den2, out2);
    final_fc  <<<ngrid4, BLK, 0, stream>>>(out2, b2, Wfc, bfc, out);
}

// Round 2
// 458.444 us; speedup vs baseline: 3.2012x; 3.2012x over previous
//
#include <hip/hip_runtime.h>
#include <math.h>

#define N_NODES 50000
#define N_EDGES 800000
#define E_TOT   (N_EDGES + N_NODES)   // 850000, self-loops appended
#define NEG_SLOPE 0.2f

// ---- workspace layout (bytes), all offsets 16-aligned ----
#define DEG_OFF    0UL          // N u32 (zeroed)
#define CUR_OFF    200000UL     // N u32 (zeroed)
#define ZERO_BYTES 400000UL
#define ROW_OFF    400000UL     // (N+1) u32 = 200,004
#define CSR_OFF    600016UL     // E_TOT i32 = 3,400,000
#define AS1_OFF    4000016UL    // N*4 f32 = 800,000
#define AD1_OFF    4800016UL    // N*4 f32
#define X2_OFF     5600016UL    // N*256 f32 = 51,200,000
#define H2_OFF     56800016UL   // N*64 f32 = 12,800,000
#define AS2_OFF    69600016UL   // N f32
#define AD2_OFF    69800016UL   // N f32  (end 70,000,016)

__device__ __forceinline__ float wave_reduce_sum(float v) {
    #pragma unroll
    for (int off = 32; off > 0; off >>= 1) v += __shfl_xor(v, off, 64);
    return v;
}
__device__ __forceinline__ float wave_reduce_max(float v) {
    #pragma unroll
    for (int off = 32; off > 0; off >>= 1) v = fmaxf(v, __shfl_xor(v, off, 64));
    return v;
}
__device__ __forceinline__ float lrelu(float v) { return v > 0.f ? v : NEG_SLOPE * v; }
__device__ __forceinline__ float elu(float v)   { return v > 0.f ? v : expf(v) - 1.f; }
__device__ __forceinline__ void edge_sd(int e, const int* __restrict__ ei, int& s, int& d) {
    if (e < N_EDGES) { s = ei[e]; d = ei[N_EDGES + e]; }
    else             { s = d = e - N_EDGES; }
}

// K1: per node, h1 = x@W1 (recomputed); alpha_s1/alpha_d1 via wave reduce.
// block 256 = 4 waves = 4 heads; grid = N_NODES
__global__ void node_prep1(const float* __restrict__ x, const float* __restrict__ W1,
                           const float* __restrict__ a_src, const float* __restrict__ a_dst,
                           float* __restrict__ alpha_s, float* __restrict__ alpha_d) {
    int n = blockIdx.x;
    int head = threadIdx.x >> 6;
    int lane = threadIdx.x & 63;
    float x0 = x[n*3+0], x1 = x[n*3+1], x2 = x[n*3+2];
    int j = head*64 + lane;
    float hv = x0*W1[j] + x1*W1[256+j] + x2*W1[512+j];
    float ps = wave_reduce_sum(hv * a_src[j]);
    float pd = wave_reduce_sum(hv * a_dst[j]);
    if (lane == 0) { alpha_s[n*4+head] = ps; alpha_d[n*4+head] = pd; }
}

// K2: histogram of dst degree (self-loops included)
__global__ void hist_deg(const int* __restrict__ ei, unsigned* __restrict__ deg) {
    int e = blockIdx.x*blockDim.x + threadIdx.x;
    if (e >= E_TOT) return;
    int d = (e < N_EDGES) ? ei[N_EDGES + e] : e - N_EDGES;
    atomicAdd(&deg[d], 1u);
}

// K3: exclusive scan of deg -> row_start[0..N]; single block, 1024 threads,
// hierarchical shfl scan (wave scan + wave-sum scan), 4 barriers per 1024-chunk.
__global__ void scan_deg(const unsigned* __restrict__ deg, unsigned* __restrict__ row_start) {
    __shared__ unsigned wsum[16];
    __shared__ unsigned s_carry;
    int lane = threadIdx.x & 63, w = threadIdx.x >> 6;
    if (threadIdx.x == 0) s_carry = 0;
    __syncthreads();
    for (int base = 0; base < N_NODES; base += 1024) {
        int i = base + threadIdx.x;
        unsigned orig = (i < N_NODES) ? deg[i] : 0u;
        unsigned v = orig;
        #pragma unroll
        for (int off = 1; off < 64; off <<= 1) {
            unsigned t = __shfl_up(v, off, 64);
            if (lane >= off) v += t;
        }
        if (lane == 63) wsum[w] = v;
        __syncthreads();
        if (w == 0) {
            unsigned ws = (lane < 16) ? wsum[lane] : 0u;
            #pragma unroll
            for (int off = 1; off < 16; off <<= 1) {
                unsigned t = __shfl_up(ws, off, 64);
                if (lane >= off) ws += t;
            }
            if (lane < 16) wsum[lane] = ws;  // inclusive wave sums
        }
        __syncthreads();
        unsigned woff  = (w == 0) ? 0u : wsum[w-1];
        unsigned carry = s_carry;
        if (i < N_NODES) row_start[i] = carry + woff + v - orig;  // exclusive
        __syncthreads();
        if (threadIdx.x == 1023) s_carry = carry + wsum[15];
        __syncthreads();
    }
    if (threadIdx.x == 0) row_start[N_NODES] = s_carry;  // == E_TOT
}

// K4: scatter src into CSR slots
__global__ void scatter_csr(const int* __restrict__ ei, const unsigned* __restrict__ row_start,
                            unsigned* __restrict__ cursor, int* __restrict__ csr_src) {
    int e = blockIdx.x*blockDim.x + threadIdx.x;
    if (e >= E_TOT) return;
    int s, d; edge_sd(e, ei, s, d);
    unsigned pos = atomicAdd(&cursor[d], 1u);
    csr_src[row_start[d] + pos] = s;
}

// K5: fused layer-1 softmax + aggregate + bias + ELU. One wave per node,
// lane = channel within head, 4 heads in registers. No atomics.
__global__ void gat1_node(const int* __restrict__ csr_src, const unsigned* __restrict__ row_start,
                          const float* __restrict__ x, const float* __restrict__ W1,
                          const float* __restrict__ as1, const float* __restrict__ ad1,
                          const float* __restrict__ b1, float* __restrict__ x2out) {
    int n = blockIdx.x*4 + (threadIdx.x >> 6);
    int lane = threadIdx.x & 63;
    if (n >= N_NODES) return;
    unsigned r0 = row_start[n], r1 = row_start[n+1];
    float4 adv = *(const float4*)(ad1 + (size_t)n*4);
    // hoist my 4 channels' weights (j = h*64+lane)
    float w0[4], w1[4], w2[4];
    #pragma unroll
    for (int h = 0; h < 4; ++h) {
        int j = h*64 + lane;
        w0[h] = W1[j]; w1[h] = W1[256+j]; w2[h] = W1[512+j];
    }
    // phase A: lane-parallel max over edges
    float m[4] = {-INFINITY, -INFINITY, -INFINITY, -INFINITY};
    for (unsigned c = r0 + lane; c < r1; c += 64) {
        int s = csr_src[c];
        float4 as = *(const float4*)(as1 + (size_t)s*4);
        m[0] = fmaxf(m[0], lrelu(as.x+adv.x));
        m[1] = fmaxf(m[1], lrelu(as.y+adv.y));
        m[2] = fmaxf(m[2], lrelu(as.z+adv.z));
        m[3] = fmaxf(m[3], lrelu(as.w+adv.w));
    }
    #pragma unroll
    for (int h = 0; h < 4; ++h) m[h] = wave_reduce_max(m[h]);
    // phase B: lane-parallel exp-sum
    float den[4] = {0.f, 0.f, 0.f, 0.f};
    for (unsigned c = r0 + lane; c < r1; c += 64) {
        int s = csr_src[c];
        float4 as = *(const float4*)(as1 + (size_t)s*4);
        den[0] += expf(lrelu(as.x+adv.x) - m[0]);
        den[1] += expf(lrelu(as.y+adv.y) - m[1]);
        den[2] += expf(lrelu(as.z+adv.z) - m[2]);
        den[3] += expf(lrelu(as.w+adv.w) - m[3]);
    }
    #pragma unroll
    for (int h = 0; h < 4; ++h) den[h] = wave_reduce_sum(den[h]) + 1e-16f;
    // phase C: lane loads one edge's data; shfl-broadcast accumulate
    float acc[4] = {0.f, 0.f, 0.f, 0.f};
    for (unsigned c0 = r0; c0 < r1; c0 += 64) {
        int cnt = (int)min(64u, r1 - c0);
        float xa = 0.f, xb = 0.f, xc = 0.f, al[4] = {0.f, 0.f, 0.f, 0.f};
        if (lane < cnt) {
            int s = csr_src[c0 + lane];
            xa = x[s*3+0]; xb = x[s*3+1]; xc = x[s*3+2];
            float4 as = *(const float4*)(as1 + (size_t)s*4);
            al[0] = expf(lrelu(as.x+adv.x) - m[0]) / den[0];
            al[1] = expf(lrelu(as.y+adv.y) - m[1]) / den[1];
            al[2] = expf(lrelu(as.z+adv.z) - m[2]) / den[2];
            al[3] = expf(lrelu(as.w+adv.w) - m[3]) / den[3];
        }
        for (int t = 0; t < cnt; ++t) {
            float ta = __shfl(xa, t, 64), tb = __shfl(xb, t, 64), tc = __shfl(xc, t, 64);
            #pragma unroll
            for (int h = 0; h < 4; ++h) {
                float a = __shfl(al[h], t, 64);
                acc[h] += (ta*w0[h] + tb*w1[h] + tc*w2[h]) * a;
            }
        }
    }
    // epilogue: bias + ELU, coalesced store (becomes x2)
    #pragma unroll
    for (int h = 0; h < 4; ++h) {
        int j = h*64 + lane;
        x2out[(size_t)n*256 + j] = elu(acc[h] + b1[j]);
    }
}

// K6: h2 = x2 @ W2 (256->64); alpha_s2/alpha_d2. One wave per node.
__global__ void node_prep2(const float* __restrict__ x2, const float* __restrict__ W2,
                           const float* __restrict__ a_src, const float* __restrict__ a_dst,
                           float* __restrict__ h2, float* __restrict__ alpha_s,
                           float* __restrict__ alpha_d) {
    int n = blockIdx.x*4 + (threadIdx.x >> 6);
    int lane = threadIdx.x & 63;
    if (n >= N_NODES) return;
    const float* xr = x2 + (size_t)n*256;
    float acc = 0.f;
    #pragma unroll
    for (int k0 = 0; k0 < 256; k0 += 64) {
        float xk = xr[k0 + lane];           // coalesced chunk
        #pragma unroll
        for (int k = 0; k < 64; ++k)
            acc += __shfl(xk, k, 64) * W2[(k0+k)*64 + lane];
    }
    h2[(size_t)n*64 + lane] = acc;
    float ps = wave_reduce_sum(acc * a_src[lane]);
    float pd = wave_reduce_sum(acc * a_dst[lane]);
    if (lane == 0) { alpha_s[n] = ps; alpha_d[n] = pd; }
}

// K7: fused layer-2 softmax + aggregate + bias + ELU + FC + sigmoid.
// One wave per node, lane = channel. No atomics.
__global__ void gat2_node(const int* __restrict__ csr_src, const unsigned* __restrict__ row_start,
                          const float* __restrict__ h2, const float* __restrict__ as2,
                          const float* __restrict__ ad2, const float* __restrict__ b2,
                          const float* __restrict__ Wfc, const float* __restrict__ bfc,
                          float* __restrict__ out) {
    int n = blockIdx.x*4 + (threadIdx.x >> 6);
    int lane = threadIdx.x & 63;
    if (n >= N_NODES) return;
    unsigned r0 = row_start[n], r1 = row_start[n+1];
    float adv = ad2[n];
    // phase A: max
    float m = -INFINITY;
    for (unsigned c = r0 + lane; c < r1; c += 64)
        m = fmaxf(m, lrelu(as2[csr_src[c]] + adv));
    m = wave_reduce_max(m);
    // phase B: exp-sum
    float den = 0.f;
    for (unsigned c = r0 + lane; c < r1; c += 64)
        den += expf(lrelu(as2[csr_src[c]] + adv) - m);
    den = wave_reduce_sum(den) + 1e-16f;
    // phase C: gather-accumulate
    float acc = 0.f;
    for (unsigned c0 = r0; c0 < r1; c0 += 64) {
        int cnt = (int)min(64u, r1 - c0);
        int s = 0; float al = 0.f;
        if (lane < cnt) {
            s = csr_src[c0 + lane];
            al = expf(lrelu(as2[s] + adv) - m) / den;
        }
        for (int t = 0; t < cnt; ++t) {
            int   st = __shfl(s,  t, 64);
            float a  = __shfl(al, t, 64);
            acc += h2[(size_t)st*64 + lane] * a;
        }
    }
    // epilogue: bias + ELU + FC + sigmoid
    float v = elu(acc + b2[lane]);
    float sum = wave_reduce_sum(v * Wfc[lane]);
    if (lane == 0) out[n] = 1.f / (1.f + expf(-(sum + bfc[0])));
}

extern "C" void kernel_launch(void* const* d_in, const int* in_sizes, int n_in,
                              void* d_out, int out_size, void* d_ws, size_t ws_size,
                              hipStream_t stream) {
    const float* x      = (const float*)d_in[0];
    const int*   ei     = (const int*)  d_in[1];
    const float* W1     = (const float*)d_in[2];
    const float* a_src1 = (const float*)d_in[3];
    const float* a_dst1 = (const float*)d_in[4];
    const float* b1     = (const float*)d_in[5];
    const float* W2     = (const float*)d_in[6];
    const float* a_src2 = (const float*)d_in[7];
    const float* a_dst2 = (const float*)d_in[8];
    const float* b2     = (const float*)d_in[9];
    const float* Wfc    = (const float*)d_in[10];
    const float* bfc    = (const float*)d_in[11];
    float* out = (float*)d_out;

    char* ws = (char*)d_ws;
    unsigned* deg   = (unsigned*)(ws + DEG_OFF);
    unsigned* cur   = (unsigned*)(ws + CUR_OFF);
    unsigned* row   = (unsigned*)(ws + ROW_OFF);
    int*      csr   = (int*)     (ws + CSR_OFF);
    float*    as1   = (float*)   (ws + AS1_OFF);
    float*    ad1   = (float*)   (ws + AD1_OFF);
    float*    x2    = (float*)   (ws + X2_OFF);
    float*    h2    = (float*)   (ws + H2_OFF);
    float*    as2   = (float*)   (ws + AS2_OFF);
    float*    ad2   = (float*)   (ws + AD2_OFF);

    hipMemsetAsync(d_ws, 0, ZERO_BYTES, stream);  // deg + cursor only

    const int BLK = 256;
    const int egrid  = (E_TOT + BLK - 1) / BLK;   // 1 thread / edge
    const int ngrid4 = (N_NODES + 3) / 4;         // 1 wave / node

    node_prep1 <<<N_NODES, BLK, 0, stream>>>(x, W1, a_src1, a_dst1, as1, ad1);
    hist_deg   <<<egrid, BLK, 0, stream>>>(ei, deg);
    scan_deg   <<<1, 1024, 0, stream>>>(deg, row);
    scatter_csr<<<egrid, BLK, 0, stream>>>(ei, row, cur, csr);
    gat1_node  <<<ngrid4, BLK, 0, stream>>>(csr, row, x, W1, as1, ad1, b1, x2);
    node_prep2 <<<ngrid4, BLK, 0, stream>>>(x2, W2, a_src2, a_dst2, h2, as2, ad2);
    gat2_node  <<<ngrid4, BLK, 0, stream>>>(csr, row, h2, as2, ad2, b2, Wfc, bfc, out);
}

// Round 3
// 269.919 us; speedup vs baseline: 5.4371x; 1.6985x over previous
//
#include <hip/hip_runtime.h>
#include <math.h>

#define N_NODES 50000
#define N_EDGES 800000
#define E_TOT   (N_EDGES + N_NODES)   // 850000, self-loops appended
#define NEG_SLOPE 0.2f

// ---- workspace layout (bytes), 16-aligned ----
#define DEG_OFF    0UL           // N u32 (zeroed)
#define CUR_OFF    200000UL      // N u32 (zeroed)
#define ZERO_BYTES 400000UL
#define ROW_OFF    400000UL      // (N+1) u32, pad -> 600016
#define CSR_OFF    600016UL      // E_TOT i32 = 3,400,000
#define VS1_OFF    4000016UL     // 12 f32 (pad 64)
#define VD1_OFF    4000080UL     // 12 f32 (pad to 4000160)
#define AS1_OFF    4000160UL     // N*4 f32 = 800,000
#define AD1_OFF    4800160UL     // N*4 f32
#define X2_OFF     5600160UL     // N*256 f32 = 51,200,000
#define H2_OFF     56800160UL    // N*64 f32 = 12,800,000
#define AS2_OFF    69600160UL    // N f32
#define AD2_OFF    69800160UL    // N f32 (end 70,000,160)

__device__ __forceinline__ float wave_reduce_sum(float v) {
    #pragma unroll
    for (int off = 32; off > 0; off >>= 1) v += __shfl_xor(v, off, 64);
    return v;
}
// reductions within a 16-lane group (groups are 16-aligned, xor<16 stays inside)
__device__ __forceinline__ float grp_reduce_sum(float v) {
    #pragma unroll
    for (int off = 8; off > 0; off >>= 1) v += __shfl_xor(v, off, 64);
    return v;
}
__device__ __forceinline__ float grp_reduce_max(float v) {
    #pragma unroll
    for (int off = 8; off > 0; off >>= 1) v = fmaxf(v, __shfl_xor(v, off, 64));
    return v;
}
__device__ __forceinline__ float lrelu(float v) { return v > 0.f ? v : NEG_SLOPE * v; }
__device__ __forceinline__ float elu(float v)   { return v > 0.f ? v : expf(v) - 1.f; }

// K0: fold W1 through a_src1/a_dst1: v[k][h] = sum_c W1[k][h*64+c]*a[h][c]. 1 block.
__global__ void precompute_v1(const float* __restrict__ W1, const float* __restrict__ a_s,
                              const float* __restrict__ a_d, float* __restrict__ vs,
                              float* __restrict__ vd) {
    int h = threadIdx.x >> 6;        // wave = head
    int lane = threadIdx.x & 63;
    float avs = a_s[h*64 + lane], avd = a_d[h*64 + lane];
    #pragma unroll
    for (int k = 0; k < 3; ++k) {
        float w = W1[k*256 + h*64 + lane];
        float ps = wave_reduce_sum(w * avs);
        float pd = wave_reduce_sum(w * avd);
        if (lane == 0) { vs[k*4+h] = ps; vd[k*4+h] = pd; }
    }
}

// K1: per-node alphas from folded vectors: 24 FMAs per node.
__global__ void node_alpha1(const float* __restrict__ x, const float* __restrict__ vs,
                            const float* __restrict__ vd, float* __restrict__ as1,
                            float* __restrict__ ad1) {
    int n = blockIdx.x*blockDim.x + threadIdx.x;
    if (n >= N_NODES) return;
    float x0 = x[n*3+0], x1 = x[n*3+1], x2v = x[n*3+2];
    float4 s, d;
    s.x = x0*vs[0] + x1*vs[4] + x2v*vs[8];
    s.y = x0*vs[1] + x1*vs[5] + x2v*vs[9];
    s.z = x0*vs[2] + x1*vs[6] + x2v*vs[10];
    s.w = x0*vs[3] + x1*vs[7] + x2v*vs[11];
    d.x = x0*vd[0] + x1*vd[4] + x2v*vd[8];
    d.y = x0*vd[1] + x1*vd[5] + x2v*vd[9];
    d.z = x0*vd[2] + x1*vd[6] + x2v*vd[10];
    d.w = x0*vd[3] + x1*vd[7] + x2v*vd[11];
    *(float4*)(as1 + (size_t)n*4) = s;
    *(float4*)(ad1 + (size_t)n*4) = d;
}

// K2: histogram of dst degree (self-loops included)
__global__ void hist_deg(const int* __restrict__ ei, unsigned* __restrict__ deg) {
    int e = blockIdx.x*blockDim.x + threadIdx.x;
    if (e >= E_TOT) return;
    int d = (e < N_EDGES) ? ei[N_EDGES + e] : e - N_EDGES;
    atomicAdd(&deg[d], 1u);
}

// K3: exclusive scan of deg -> row_start[0..N]; single block of 1024.
__global__ void scan_deg(const unsigned* __restrict__ deg, unsigned* __restrict__ row_start) {
    __shared__ unsigned wsum[16];
    __shared__ unsigned s_carry;
    int lane = threadIdx.x & 63, w = threadIdx.x >> 6;
    if (threadIdx.x == 0) s_carry = 0;
    __syncthreads();
    for (int base = 0; base < N_NODES; base += 1024) {
        int i = base + threadIdx.x;
        unsigned orig = (i < N_NODES) ? deg[i] : 0u;
        unsigned v = orig;
        #pragma unroll
        for (int off = 1; off < 64; off <<= 1) {
            unsigned t = __shfl_up(v, off, 64);
            if (lane >= off) v += t;
        }
        if (lane == 63) wsum[w] = v;
        __syncthreads();
        if (w == 0) {
            unsigned ws = (lane < 16) ? wsum[lane] : 0u;
            #pragma unroll
            for (int off = 1; off < 16; off <<= 1) {
                unsigned t = __shfl_up(ws, off, 64);
                if (lane >= off) ws += t;
            }
            if (lane < 16) wsum[lane] = ws;
        }
        __syncthreads();
        unsigned woff  = (w == 0) ? 0u : wsum[w-1];
        unsigned carry = s_carry;
        if (i < N_NODES) row_start[i] = carry + woff + v - orig;
        __syncthreads();
        if (threadIdx.x == 1023) s_carry = carry + wsum[15];
        __syncthreads();
    }
    if (threadIdx.x == 0) row_start[N_NODES] = s_carry;
}

// K4: scatter src into CSR slots
__global__ void scatter_csr(const int* __restrict__ ei, const unsigned* __restrict__ row_start,
                            unsigned* __restrict__ cursor, int* __restrict__ csr_src) {
    int e = blockIdx.x*blockDim.x + threadIdx.x;
    if (e >= E_TOT) return;
    int s, d;
    if (e < N_EDGES) { s = ei[e]; d = ei[N_EDGES + e]; }
    else             { s = d = e - N_EDGES; }
    unsigned pos = atomicAdd(&cursor[d], 1u);
    csr_src[row_start[d] + pos] = s;
}

// K5: fused layer-1. 16 lanes per node, 4 nodes/wave, 16 nodes/block.
// Aggregation factored: g[h][k] = sum_e alpha_e^h * x[src_e][k]  (12 floats),
// then out[j] = elu(sum_k W1[k][j]*g[h][k] + b1[j]).
__global__ void gat1_node(const int* __restrict__ csr_src, const unsigned* __restrict__ row_start,
                          const float* __restrict__ x, const float* __restrict__ W1,
                          const float* __restrict__ as1, const float* __restrict__ ad1,
                          const float* __restrict__ b1, float* __restrict__ x2out) {
    int lane = threadIdx.x & 63, w = threadIdx.x >> 6;
    int subl = lane & 15, grp = lane >> 4;
    int n = blockIdx.x*16 + w*4 + grp;          // grid sized exactly: n < N_NODES
    unsigned r0 = row_start[n], r1 = row_start[n+1];
    float4 adv = *(const float4*)(ad1 + (size_t)n*4);
    // phase A: max per head
    float m0=-INFINITY, m1=-INFINITY, m2=-INFINITY, m3=-INFINITY;
    for (unsigned c = r0 + subl; c < r1; c += 16) {
        int s = csr_src[c];
        float4 as = *(const float4*)(as1 + (size_t)s*4);
        m0 = fmaxf(m0, lrelu(as.x+adv.x));
        m1 = fmaxf(m1, lrelu(as.y+adv.y));
        m2 = fmaxf(m2, lrelu(as.z+adv.z));
        m3 = fmaxf(m3, lrelu(as.w+adv.w));
    }
    m0 = grp_reduce_max(m0); m1 = grp_reduce_max(m1);
    m2 = grp_reduce_max(m2); m3 = grp_reduce_max(m3);
    // phase B: exp-sum per head
    float d0=0.f, d1=0.f, d2=0.f, d3=0.f;
    for (unsigned c = r0 + subl; c < r1; c += 16) {
        int s = csr_src[c];
        float4 as = *(const float4*)(as1 + (size_t)s*4);
        d0 += expf(lrelu(as.x+adv.x) - m0);
        d1 += expf(lrelu(as.y+adv.y) - m1);
        d2 += expf(lrelu(as.z+adv.z) - m2);
        d3 += expf(lrelu(as.w+adv.w) - m3);
    }
    float r_0 = 1.f/(grp_reduce_sum(d0) + 1e-16f);
    float r_1 = 1.f/(grp_reduce_sum(d1) + 1e-16f);
    float r_2 = 1.f/(grp_reduce_sum(d2) + 1e-16f);
    float r_3 = 1.f/(grp_reduce_sum(d3) + 1e-16f);
    // phase C: accumulate g[h][k] (alpha without /den; scale after reduce)
    float g00=0,g01=0,g02=0, g10=0,g11=0,g12=0, g20=0,g21=0,g22=0, g30=0,g31=0,g32=0;
    for (unsigned c = r0 + subl; c < r1; c += 16) {
        int s = csr_src[c];
        float4 as = *(const float4*)(as1 + (size_t)s*4);
        float e0 = expf(lrelu(as.x+adv.x) - m0);
        float e1 = expf(lrelu(as.y+adv.y) - m1);
        float e2 = expf(lrelu(as.z+adv.z) - m2);
        float e3 = expf(lrelu(as.w+adv.w) - m3);
        float xa = x[s*3+0], xb = x[s*3+1], xc = x[s*3+2];
        g00 = fmaf(e0,xa,g00); g01 = fmaf(e0,xb,g01); g02 = fmaf(e0,xc,g02);
        g10 = fmaf(e1,xa,g10); g11 = fmaf(e1,xb,g11); g12 = fmaf(e1,xc,g12);
        g20 = fmaf(e2,xa,g20); g21 = fmaf(e2,xb,g21); g22 = fmaf(e2,xc,g22);
        g30 = fmaf(e3,xa,g30); g31 = fmaf(e3,xb,g31); g32 = fmaf(e3,xc,g32);
    }
    g00 = grp_reduce_sum(g00)*r_0; g01 = grp_reduce_sum(g01)*r_0; g02 = grp_reduce_sum(g02)*r_0;
    g10 = grp_reduce_sum(g10)*r_1; g11 = grp_reduce_sum(g11)*r_1; g12 = grp_reduce_sum(g12)*r_1;
    g20 = grp_reduce_sum(g20)*r_2; g21 = grp_reduce_sum(g21)*r_2; g22 = grp_reduce_sum(g22)*r_2;
    g30 = grp_reduce_sum(g30)*r_3; g31 = grp_reduce_sum(g31)*r_3; g32 = grp_reduce_sum(g32)*r_3;
    // epilogue: 256 channels across 16 lanes; h = i>>2 is compile-time per i.
    float* xrow = x2out + (size_t)n*256;
    #pragma unroll
    for (int i = 0; i < 16; ++i) {
        int j = i*16 + subl;
        float ga, gb, gc;
        if      (i < 4)  { ga=g00; gb=g01; gc=g02; }
        else if (i < 8)  { ga=g10; gb=g11; gc=g12; }
        else if (i < 12) { ga=g20; gb=g21; gc=g22; }
        else             { ga=g30; gb=g31; gc=g32; }
        float val = ga*W1[j] + gb*W1[256+j] + gc*W1[512+j] + b1[j];
        xrow[j] = elu(val);
    }
}

// K6: h2 = x2 @ W2 (256->64) tiled GEMM + alpha_s2/ad2.
// 32 nodes/block, LDS row-major staging (stride 260), 8 acc per thread.
__global__ __launch_bounds__(256) void node_prep2(
        const float* __restrict__ x2, const float* __restrict__ W2,
        const float* __restrict__ a_src, const float* __restrict__ a_dst,
        float* __restrict__ h2, float* __restrict__ alpha_s, float* __restrict__ alpha_d) {
    __shared__ float xr[32][260];
    int n0 = blockIdx.x * 32;
    int t = threadIdx.x;
    int nn = t >> 3, q = t & 7;
    if (n0 + nn < N_NODES) {
        const float4* src = (const float4*)(x2 + (size_t)(n0+nn)*256);
        #pragma unroll
        for (int r = 0; r < 8; ++r) {
            int f = q + r*8;
            *(float4*)(&xr[nn][f*4]) = src[f];
        }
    }
    __syncthreads();
    int w = t >> 6, lane = t & 63;
    float a2s = a_src[lane], a2d = a_dst[lane];
    float acc[8] = {0,0,0,0,0,0,0,0};
    const int jn0 = w*8;
    for (int k0 = 0; k0 < 256; k0 += 4) {
        float w0 = W2[(k0+0)*64 + lane];
        float w1 = W2[(k0+1)*64 + lane];
        float w2 = W2[(k0+2)*64 + lane];
        float w3 = W2[(k0+3)*64 + lane];
        #pragma unroll
        for (int j = 0; j < 8; ++j) {
            float4 xv = *(const float4*)(&xr[jn0+j][k0]);
            acc[j] = fmaf(xv.x, w0, acc[j]);
            acc[j] = fmaf(xv.y, w1, acc[j]);
            acc[j] = fmaf(xv.z, w2, acc[j]);
            acc[j] = fmaf(xv.w, w3, acc[j]);
        }
    }
    #pragma unroll
    for (int j = 0; j < 8; ++j) {
        int n = n0 + jn0 + j;
        if (n < N_NODES) {
            h2[(size_t)n*64 + lane] = acc[j];
            float ps = wave_reduce_sum(acc[j] * a2s);
            float pd = wave_reduce_sum(acc[j] * a2d);
            if (lane == 0) { alpha_s[n] = ps; alpha_d[n] = pd; }
        }
    }
}

// K7: fused layer-2 + FC + sigmoid. 16 lanes/node (4 channels each), 4 nodes/wave.
__global__ void gat2_node(const int* __restrict__ csr_src, const unsigned* __restrict__ row_start,
                          const float* __restrict__ h2, const float* __restrict__ as2,
                          const float* __restrict__ ad2, const float* __restrict__ b2,
                          const float* __restrict__ Wfc, const float* __restrict__ bfc,
                          float* __restrict__ out) {
    int lane = threadIdx.x & 63, w = threadIdx.x >> 6;
    int subl = lane & 15, grp = lane >> 4;
    int n = blockIdx.x*16 + w*4 + grp;          // exact grid
    unsigned r0 = row_start[n], r1 = row_start[n+1];
    float adv = ad2[n];
    float m = -INFINITY;
    for (unsigned c = r0 + subl; c < r1; c += 16)
        m = fmaxf(m, lrelu(as2[csr_src[c]] + adv));
    m = grp_reduce_max(m);
    float den = 0.f;
    for (unsigned c = r0 + subl; c < r1; c += 16)
        den += expf(lrelu(as2[csr_src[c]] + adv) - m);
    float rden = 1.f/(grp_reduce_sum(den) + 1e-16f);
    float acc0=0.f, acc1=0.f, acc2=0.f, acc3=0.f;
    for (unsigned c = r0; c < r1; ++c) {         // serial edges; 16 lanes split channels
        int s = csr_src[c];
        float al = expf(lrelu(as2[s] + adv) - m) * rden;
        const float* hr = h2 + (size_t)s*64 + subl;
        acc0 = fmaf(hr[0],  al, acc0);
        acc1 = fmaf(hr[16], al, acc1);
        acc2 = fmaf(hr[32], al, acc2);
        acc3 = fmaf(hr[48], al, acc3);
    }
    float v0 = elu(acc0 + b2[subl]);
    float v1 = elu(acc1 + b2[subl+16]);
    float v2 = elu(acc2 + b2[subl+32]);
    float v3 = elu(acc3 + b2[subl+48]);
    float part = v0*Wfc[subl] + v1*Wfc[subl+16] + v2*Wfc[subl+32] + v3*Wfc[subl+48];
    part = grp_reduce_sum(part);
    if (subl == 0) out[n] = 1.f/(1.f + expf(-(part + bfc[0])));
}

extern "C" void kernel_launch(void* const* d_in, const int* in_sizes, int n_in,
                              void* d_out, int out_size, void* d_ws, size_t ws_size,
                              hipStream_t stream) {
    const float* x      = (const float*)d_in[0];
    const int*   ei     = (const int*)  d_in[1];
    const float* W1     = (const float*)d_in[2];
    const float* a_src1 = (const float*)d_in[3];
    const float* a_dst1 = (const float*)d_in[4];
    const float* b1     = (const float*)d_in[5];
    const float* W2     = (const float*)d_in[6];
    const float* a_src2 = (const float*)d_in[7];
    const float* a_dst2 = (const float*)d_in[8];
    const float* b2     = (const float*)d_in[9];
    const float* Wfc    = (const float*)d_in[10];
    const float* bfc    = (const float*)d_in[11];
    float* out = (float*)d_out;

    char* ws = (char*)d_ws;
    unsigned* deg = (unsigned*)(ws + DEG_OFF);
    unsigned* cur = (unsigned*)(ws + CUR_OFF);
    unsigned* row = (unsigned*)(ws + ROW_OFF);
    int*      csr = (int*)     (ws + CSR_OFF);
    float*    vs1 = (float*)   (ws + VS1_OFF);
    float*    vd1 = (float*)   (ws + VD1_OFF);
    float*    as1 = (float*)   (ws + AS1_OFF);
    float*    ad1 = (float*)   (ws + AD1_OFF);
    float*    x2  = (float*)   (ws + X2_OFF);
    float*    h2  = (float*)   (ws + H2_OFF);
    float*    as2 = (float*)   (ws + AS2_OFF);
    float*    ad2 = (float*)   (ws + AD2_OFF);

    hipMemsetAsync(d_ws, 0, ZERO_BYTES, stream);  // deg + cursor

    const int BLK = 256;
    const int egrid = (E_TOT + BLK - 1) / BLK;

    precompute_v1<<<1, BLK, 0, stream>>>(W1, a_src1, a_dst1, vs1, vd1);
    node_alpha1 <<<(N_NODES + BLK - 1)/BLK, BLK, 0, stream>>>(x, vs1, vd1, as1, ad1);
    hist_deg    <<<egrid, BLK, 0, stream>>>(ei, deg);
    scan_deg    <<<1, 1024, 0, stream>>>(deg, row);
    scatter_csr <<<egrid, BLK, 0, stream>>>(ei, row, cur, csr);
    gat1_node   <<<N_NODES/16, BLK, 0, stream>>>(csr, row, x, W1, as1, ad1, b1, x2);
    node_prep2  <<<(N_NODES + 31)/32, BLK, 0, stream>>>(x2, W2, a_src2, a_dst2, h2, as2, ad2);
    gat2_node   <<<N_NODES/16, BLK, 0, stream>>>(csr, row, h2, as2, ad2, b2, Wfc, bfc, out);
}